// Round 5
// baseline (411.668 us; speedup 1.0000x reference)
//
#include <hip/hip_runtime.h>
#include <math.h>

#define SS 512
#define BB 256
#define DIN 202
#define HH 100
#define TT 19

typedef short short8 __attribute__((ext_vector_type(8)));
typedef float f32x4 __attribute__((ext_vector_type(4)));

#define MFMA16(A, B, C) __builtin_amdgcn_mfma_f32_16x16x32_bf16(A, B, C, 0, 0, 0)

__device__ __forceinline__ float rl(float v, int i) {
    return __int_as_float(__builtin_amdgcn_readlane(__float_as_int(v), i));
}
__device__ __forceinline__ float rfl(float v) {
    return __int_as_float(__builtin_amdgcn_readfirstlane(__float_as_int(v)));
}
__device__ __forceinline__ unsigned short f2bf(float f) {
  unsigned u = __float_as_uint(f);
  u += 0x7fff + ((u >> 16) & 1);   // RNE
  return (unsigned short)(u >> 16);
}
__device__ __forceinline__ float bf2f(unsigned v) {
  return __int_as_float((int)(v << 16));
}
__device__ __forceinline__ float fast_tanh(float z) {
  float e = __expf(2.f * z);
  return (e - 1.f) * __fdividef(1.f, e + 1.f);
}
__device__ __forceinline__ void gl_lds16(const void* g, void* l) {
  __builtin_amdgcn_global_load_lds(
      (const __attribute__((address_space(1))) unsigned int*)g,
      (__attribute__((address_space(3))) unsigned int*)l, 16, 0, 0);
}
__device__ __forceinline__ uint2 pack_tanh(f32x4 a) {
  float h0 = fast_tanh(a[0]), h1 = fast_tanh(a[1]);
  float h2 = fast_tanh(a[2]), h3 = fast_tanh(a[3]);
  uint2 v;
  v.x = ((unsigned)f2bf(h1) << 16) | f2bf(h0);
  v.y = ((unsigned)f2bf(h3) << 16) | f2bf(h2);
  return v;
}
__device__ __forceinline__ uint2 pack_raw(f32x4 a) {
  uint2 v;
  v.x = ((unsigned)f2bf(a[1]) << 16) | f2bf(a[0]);
  v.y = ((unsigned)f2bf(a[3]) << 16) | f2bf(a[2]);
  return v;
}
__device__ __forceinline__ f32x4 seed_from(const void* base, int off) {
  uint2 s = *(const uint2*)((const char*)base + off);
  return (f32x4){bf2f(s.x & 0xffffu), bf2f(s.x >> 16),
                 bf2f(s.y & 0xffffu), bf2f(s.y >> 16)};
}

// ---------------------------------------------------------------------------
// K0: pack W = [Wf;Wb] (200x202 fp32) into frag-linear bf16 tiles.
// ---------------------------------------------------------------------------
__global__ __launch_bounds__(256) void k_cvtW(
    const float* __restrict__ Wf, const float* __restrict__ Wb,
    unsigned short* __restrict__ Wfrag) {
  int w = blockIdx.x * 256 + threadIdx.x;
  if (w >= 7 * 13 * 64) return;
  int kc = w / (13 * 64);
  int r = w % (13 * 64);
  int ft = r >> 6, l = r & 63;
  int nn = ft * 16 + (l & 15);
  int kb = kc * 32 + (l >> 4) * 8;
  union { unsigned short s[8]; int4 v; } pk;
  #pragma unroll
  for (int e = 0; e < 8; ++e) {
    int k = kb + e;
    float vv = 0.f;
    if (k < DIN) {
      if (nn < 100) vv = Wf[(size_t)nn * DIN + k];
      else if (nn < 200) vv = Wb[(size_t)(nn - 100) * DIN + k];
    }
    pk.s[e] = f2bf(vv);
  }
  *(int4*)&Wfrag[(size_t)w * 8] = pk.v;
}

// ---------------------------------------------------------------------------
// K1: input projection (bf16 MFMA), LDS-staged epilogue into the xpT tiled
// layout k_rnn streams: xpT_d[s][bgrp(16)][u8(13)][nn(16)][8 bf16].
// ---------------------------------------------------------------------------
__global__ __launch_bounds__(256) void k_inproj(
    const float* __restrict__ x, const unsigned short* __restrict__ Wfrag,
    const float* __restrict__ bihf, const float* __restrict__ bhhf,
    const float* __restrict__ bihb, const float* __restrict__ bhhb,
    unsigned short* __restrict__ xpT0, unsigned short* __restrict__ xpT1) {
  __shared__ __align__(16) char smem_raw[28672];
  __shared__ float lbias[208];
  short* lA = (short*)smem_raw;
  short* lB = (short*)(smem_raw + 8192);
  const int t = threadIdx.x;
  const int m0 = blockIdx.x * 128;
  const int s_idx = m0 >> 8;
  const int bhalf = (m0 >> 7) & 1;
  const int wv = t >> 6, lane = t & 63;
  const int li = lane & 15;

  if (t < 208) {
    float bv = 0.f;
    if (t < 100) bv = bihf[t] + bhhf[t];
    else if (t < 200) bv = bihb[t - 100] + bhhb[t - 100];
    lbias[t] = bv;
  }

  f32x4 acc[2][13];
  #pragma unroll
  for (int mf = 0; mf < 2; ++mf)
    #pragma unroll
    for (int nf = 0; nf < 13; ++nf)
      acc[mf][nf] = (f32x4){0.f, 0.f, 0.f, 0.f};

  for (int kc = 0; kc < 7; ++kc) {
    const int k0 = kc * 32;
    __syncthreads();
    #pragma unroll
    for (int r = 0; r < 2; ++r) {
      int u = t + 256 * r;
      int ft = u >> 6, ul = u & 63;
      int i = ul & 15, kq = ul >> 4;
      int kbase = k0 + kq * 8;
      const float* src = x + (size_t)(m0 + ft * 16 + i) * DIN + kbase;
      union { unsigned short s[8]; int4 v; } pk;
      if (kbase + 7 < DIN) {
        float2 v0 = *(const float2*)(src);
        float2 v1 = *(const float2*)(src + 2);
        float2 v2 = *(const float2*)(src + 4);
        float2 v3 = *(const float2*)(src + 6);
        pk.s[0] = f2bf(v0.x); pk.s[1] = f2bf(v0.y);
        pk.s[2] = f2bf(v1.x); pk.s[3] = f2bf(v1.y);
        pk.s[4] = f2bf(v2.x); pk.s[5] = f2bf(v2.y);
        pk.s[6] = f2bf(v3.x); pk.s[7] = f2bf(v3.y);
      } else {
        #pragma unroll
        for (int e = 0; e < 8; ++e)
          pk.s[e] = (kbase + e < DIN) ? f2bf(src[e]) : 0;
      }
      *(int4*)&lA[ft * 512 + ul * 8] = pk.v;
    }
    #pragma unroll
    for (int i = 0; i < 4; ++i) {
      int j = i * 4 + wv;
      if (j < 13)
        gl_lds16(Wfrag + ((size_t)(kc * 13 + j)) * 512, &lB[j * 512]);
    }
    __syncthreads();
    short8 a0 = *(const short8*)&lA[(2 * wv + 0) * 512 + lane * 8];
    short8 a1 = *(const short8*)&lA[(2 * wv + 1) * 512 + lane * 8];
    #pragma unroll
    for (int nf = 0; nf < 13; ++nf) {
      short8 b = *(const short8*)&lB[nf * 512 + lane * 8];
      acc[0][nf] = MFMA16(a0, b, acc[0][nf]);
      acc[1][nf] = MFMA16(a1, b, acc[1][nf]);
    }
  }
  __syncthreads();
  unsigned short* ep = (unsigned short*)smem_raw;  // [128][112]
  float biasv[13];
  #pragma unroll
  for (int nf = 0; nf < 13; ++nf) biasv[nf] = lbias[nf * 16 + li];
  const int r0 = (lane >> 4) * 4;
  #pragma unroll
  for (int d = 0; d < 2; ++d) {
    if (d == 1) __syncthreads();
    #pragma unroll
    for (int mf = 0; mf < 2; ++mf) {
      int lrb = (2 * wv + mf) * 16 + r0;
      #pragma unroll
      for (int nf = 0; nf < 13; ++nf) {
        int col = nf * 16 + li;
        int c = col - 100 * d;
        if (c >= 0 && c < 100) {
          #pragma unroll
          for (int r = 0; r < 4; ++r)
            ep[(lrb + r) * 112 + c] = f2bf(acc[mf][nf][r] + biasv[nf]);
        }
      }
    }
    __syncthreads();
    unsigned short* dst0 = d ? xpT1 : xpT0;
    #pragma unroll
    for (int it = 0; it < 7; ++it) {
      int u = t + 256 * it;
      if (u < 1664) {
        int bgrpL = u / 208;
        int rem = u - bgrpL * 208;
        int u8 = rem >> 4, nn = rem & 15;
        int lr = bgrpL * 16 + nn;
        int4 v = *(const int4*)&ep[lr * 112 + u8 * 8];
        size_t off = ((((size_t)s_idx * 16 + bhalf * 8 + bgrpL) * 13 + u8) * 16 + nn) * 8;
        *(int4*)(dst0 + off) = v;
      }
    }
  }
}

// ---------------------------------------------------------------------------
// K2 v11 (R5): BARRIER-FREE wave-private RNN chains (R4 design, crash
// fixed). R4's fault: start = 16*seg-32 went NEGATIVE for seg=1 (s=-16 ->
// OOB prefetch). Fix: start = (seg<2) ? 0 : 16*seg-32. seg0: 16 exact
// steps; seg1: 32 exact steps (true trajectory from s=0); seg>=2: 32-step
// warmup + 16 outputs = 48 steps (proven truncation). Design: ONE wave owns
// an entire chain (7 hidden + 2 logit tiles, 36 MFMA/step); h round-trips
// through the wave's PRIVATE LDS ring (same-wave ds ordering, ZERO barriers).
// 4 chains/block (4 waves, 1/SIMD), 256 blocks = 1024 chains = 2dir x
// 16bgrp x 32segs. xp double-buffered via global_load_lds + counted
// s_waitcnt vmcnt(13) + sched_barrier. Layouts/math cloned from R3 (absmax 0).
// ---------------------------------------------------------------------------
__global__ __launch_bounds__(256, 1) void k_rnn(
    const unsigned short* __restrict__ xpT0, const unsigned short* __restrict__ xpT1,
    const float* __restrict__ Whf, const float* __restrict__ Whb,
    const float* __restrict__ Wtag, float* __restrict__ plogF, float* __restrict__ plogB) {
  const int bid = blockIdx.x;          // 256 blocks: dir(2) x bgrp(16) x p(8)
  const int dir = bid & 1;
  const int bgrp = (bid >> 1) & 15;
  const int b0 = bgrp * 16;
  const int p = bid >> 5;              // 0..7

  const int t = threadIdx.x;
  const int wv = t >> 6, lane = t & 63;
  const int n = lane & 15, q = lane >> 4;

  const int seg = 4 * p + wv;          // 0..31
  const int start = (seg < 2) ? 0 : (16 * seg - 32);   // NEVER negative (R4 fix)
  const int outbase = 16 * seg;
  const int nsteps = outbase + 16 - start;   // 16, 32, or 48
  const int nch = nsteps >> 2;               // 4, 8, or 12 chunks of 4 steps

  const unsigned short* xpX = dir ? xpT1 : xpT0;
  const float* Whh = dir ? Whb : Whf;
  float* plog = dir ? plogB : plogF;

  // per-chain LDS: ring 2x3328B | xpl 2x13312B | larc 5120B | dummy 16B
  __shared__ __align__(16) char chainmem[4][38416];
  char* cmem = chainmem[wv];
  short* ring = (short*)cmem;                              // 6656 B (2 slots)
  char* xpl = cmem + 6656;                                 // 26624 B
  unsigned short* larc = (unsigned short*)(cmem + 33280);  // 5120 B
  short* dummy = (short*)(cmem + 38400);                   // 16 B

  // zero ring (both slots) + dummy — same-wave, no barrier needed
  for (int i = lane; i < 1664; i += 64) ((int*)ring)[i] = 0;
  if (lane < 8) dummy[lane] = 0;

  // ---- one-time A-fragment load: all 9 tiles in this wave ----
  // w 0..6: hidden cols 16w..16w+15 (w6: 96..99+pad); w7: tags 0..15; w8: 16..18.
  short8 af[9][4];
  #pragma unroll
  for (int w = 0; w < 9; ++w) {
    const float* base = nullptr;
    if (w < 7) {
      int m = 16 * w + n;
      if (m < HH) base = Whh + (size_t)m * HH;
    } else if (w == 7) {
      if (n < TT) base = Wtag + (size_t)n * (2 * HH) + dir * HH;
    } else {
      int tA = 16 + n;
      if (tA < TT) base = Wtag + (size_t)tA * (2 * HH) + dir * HH;
    }
    #pragma unroll
    for (int q2 = 0; q2 < 4; ++q2) {
      union { unsigned short s[8]; short8 v; } pa;
      #pragma unroll
      for (int e = 0; e < 8; ++e) {
        int k = 32 * q2 + 8 * q + e;
        pa.s[e] = (base && k < HH) ? f2bf(base[k]) : 0;
      }
      af[w][q2] = pa.v;
    }
  }

  // xp unit precompute: 13 x 1KB units per 4-step chunk image [4s][3328B]
  int sl_[13], off_[13];
  #pragma unroll
  for (int u = 0; u < 13; ++u) {
    int b = u * 1024 + lane * 16;
    sl_[u] = b / 3328;
    off_[u] = b - sl_[u] * 3328 + bgrp * 3328;
  }

  auto issue_chunk = [&](int cc, int buf) {
    int s0 = start + cc * 4;
    #pragma unroll
    for (int u = 0; u < 13; ++u) {
      int s = s0 + sl_[u];
      int sq = dir ? (511 - s) : s;
      gl_lds16((const char*)xpX + (size_t)sq * 53248 + off_[u],
               xpl + buf * 13312 + u * 1024);
    }
  };

  const int offWq = ((q >> 1) * 16 + n) * 16 + (q & 1) * 8;  // + w*512
  const f32x4 z4 = {0.f, 0.f, 0.f, 0.f};

  issue_chunk(0, 0);

  for (int cc = 0; cc < nch; ++cc) {
    if (cc + 1 < nch) {
      issue_chunk(cc + 1, (cc + 1) & 1);
      asm volatile("s_waitcnt vmcnt(13)" ::: "memory");
    } else {
      asm volatile("s_waitcnt vmcnt(0)" ::: "memory");
    }
    __builtin_amdgcn_sched_barrier(0);
    const char* xb = xpl + (cc & 1) * 13312;

    #pragma unroll
    for (int sl = 0; sl < 4; ++sl) {
      const int st = cc * 4 + sl;
      const int cur = st & 1, nxt = cur ^ 1;
      short* rc = ring + cur * 1664;
      short* rn = ring + nxt * 1664;
      short8 hc0 = *(const short8*)(rc + lane * 8);
      short8 hc1 = *(const short8*)(rc + 512 + lane * 8);
      short8 hc2 = *(const short8*)(rc + 1024 + lane * 8);
      short8 hc3 = *(const short8*)((q == 0) ? (rc + 1536 + n * 8) : dummy);
      // ---- 7 hidden tiles ----
      #pragma unroll
      for (int w = 0; w < 7; ++w) {
        int o = sl * 3328 + w * 512 + offWq;
        if (o > 13304) o = 13304;   // w6 q>=2 pad rows (outputs discarded)
        f32x4 seed = seed_from(xb, o);
        f32x4 a0 = MFMA16(af[w][0], hc0, seed);
        f32x4 a1 = MFMA16(af[w][1], hc1, z4);
        a0 = MFMA16(af[w][2], hc2, a0);
        a1 = MFMA16(af[w][3], hc3, a1);
        uint2 val = pack_tanh(a0 + a1);
        if (w < 6) {
          *(uint2*)((char*)rn + (w >> 1) * 1024 +
                    ((2 * (w & 1) + (q >> 1)) * 16 + n) * 16 + (q & 1) * 8) = val;
        } else if (q == 0) {
          *(uint2*)((char*)rn + 3072 + n * 16) = val;
        }
      }
      // ---- 2 logit tiles (lag-1: use h at position start+st-1) ----
      const int ar = ((cc & 1) * 4 + sl) * 16;
      #pragma unroll
      for (int w = 7; w < 9; ++w) {
        f32x4 a0 = MFMA16(af[w][0], hc0, z4);
        f32x4 a1 = MFMA16(af[w][1], hc1, z4);
        a0 = MFMA16(af[w][2], hc2, a0);
        a1 = MFMA16(af[w][3], hc3, a1);
        uint2 v = pack_raw(a0 + a1);
        if (w == 7) *(uint2*)&larc[(ar + n) * 20 + 4 * q] = v;
        else if (q == 0) *(uint2*)&larc[(ar + n) * 20 + 16] = v;
      }
    }
    // ---- flush archive every 2 chunks (8 steps) ----
    if (cc & 1) {
      int st0 = (cc - 1) * 4;
      #pragma unroll
      for (int j = 0; j < 2; ++j) {
        int fp = lane + 64 * j;
        int sl2 = fp >> 4, nn2 = fp & 15;
        int hs = start + st0 + sl2 - 1;
        if (hs >= outbase) {
          int pos = dir ? (511 - hs) : hs;
          float* dst = plog + ((size_t)pos * 256 + b0 + nn2) * 20;
          const unsigned short* src = &larc[(sl2 * 16 + nn2) * 20];
          #pragma unroll
          for (int j5 = 0; j5 < 5; ++j5) {
            uint2 rv = *(const uint2*)&src[j5 * 4];
            float4 o;
            o.x = bf2f(rv.x & 0xffffu); o.y = bf2f(rv.x >> 16);
            o.z = bf2f(rv.y & 0xffffu); o.w = bf2f(rv.y >> 16);
            *(float4*)&dst[j5 * 4] = o;
          }
        }
      }
    }
  }

  // ---- final logits for position start+nsteps-1 (h in ring slot 0) ----
  {
    short* rc = ring;   // nsteps even -> final h in slot 0
    short8 hc0 = *(const short8*)(rc + lane * 8);
    short8 hc1 = *(const short8*)(rc + 512 + lane * 8);
    short8 hc2 = *(const short8*)(rc + 1024 + lane * 8);
    short8 hc3 = *(const short8*)((q == 0) ? (rc + 1536 + n * 8) : dummy);
    int hs = start + nsteps - 1;
    int pos = dir ? (511 - hs) : hs;
    float* dst = plog + ((size_t)pos * 256 + b0 + n) * 20;
    #pragma unroll
    for (int w = 7; w < 9; ++w) {
      f32x4 a0 = MFMA16(af[w][0], hc0, z4);
      f32x4 a1 = MFMA16(af[w][1], hc1, z4);
      a0 = MFMA16(af[w][2], hc2, a0);
      a1 = MFMA16(af[w][3], hc3, a1);
      f32x4 a = a0 + a1;
      if (w == 7) {
        #pragma unroll
        for (int r = 0; r < 4; ++r) dst[4 * q + r] = a[r];
      } else if (q == 0) {
        #pragma unroll
        for (int r = 0; r < 4; ++r) dst[16 + r] = a[r];
      }
    }
  }
}

// ---------------------------------------------------------------------------
// K4 (FUSED softmax+CRF): one wave per sequence (n = s index, L = BB).
// ---------------------------------------------------------------------------
__global__ __launch_bounds__(256) void k_crf(
    const float* __restrict__ plogF, const float* __restrict__ plogB,
    const float* __restrict__ btag, const int* __restrict__ y,
    const float* __restrict__ start, const float* __restrict__ endt,
    const float* __restrict__ trans, float* __restrict__ out) {
  __shared__ float ltr[TT * TT];
  __shared__ float ltb[20];
  __shared__ float lem[4][64 * 21];
  const int t = threadIdx.x;
  const int wave = t >> 6, lane = t & 63;
  const int n = blockIdx.x * 4 + wave;
  for (int i = t; i < TT * TT; i += 256) ltr[i] = trans[i];
  if (t < 20) ltb[t] = (t < TT) ? btag[t] : 0.f;
  __syncthreads();
  const int* yn = y + n * BB;
  float Ereg[TT];
  #pragma unroll
  for (int i = 0; i < TT; ++i) Ereg[i] = (lane < TT) ? __expf(ltr[i * TT + lane]) : 0.f;
  float num = 0.f;
  float alpha = -1e30f;
  for (int c = 0; c < 4; ++c) {
    const size_t gbase = ((size_t)n * BB + c * 64) * 20;
    for (int u = lane; u < 1280; u += 64) {
      int row = u / 20, col = u - row * 20;
      lem[wave][row * 21 + col] = plogF[gbase + u] + plogB[gbase + u] + ltb[col];
    }
    {
      float vv[TT];
      float mx = -1e30f;
      #pragma unroll
      for (int j = 0; j < TT; ++j) { vv[j] = lem[wave][lane * 21 + j]; mx = fmaxf(mx, vv[j]); }
      float ssum = 0.f;
      #pragma unroll
      for (int j = 0; j < TT; ++j) { vv[j] = __expf(vv[j] - mx); ssum += vv[j]; }
      float inv = __fdividef(1.f, ssum);
      #pragma unroll
      for (int j = 0; j < TT; ++j) lem[wave][lane * 21 + j] = vv[j] * inv;
    }
    {
      int l = c * 64 + lane;
      int yt = yn[l];
      num += lem[wave][lane * 21 + yt];
      if (l < BB - 1) num += ltr[yt * TT + yn[l + 1]];
    }
    int llstart = 0;
    if (c == 0) {
      alpha = (lane < TT) ? (start[lane] + lem[wave][lane]) : -1e30f;
      llstart = 1;
    }
    for (int ll = llstart; ll < 64; ++ll) {
      float m = rfl(alpha);
      float ea = __expf(alpha - m);
      float s0 = 0.f, s1 = 0.f;
      #pragma unroll
      for (int i = 0; i < TT; i += 2) {
        s0 = fmaf(rl(ea, i), Ereg[i], s0);
        if (i + 1 < TT) s1 = fmaf(rl(ea, i + 1), Ereg[i + 1], s1);
      }
      float ssum = s0 + s1;
      float em_l = (lane < TT) ? lem[wave][ll * 21 + lane] : 0.f;
      alpha = em_l + m + __logf(ssum);
    }
  }
  #pragma unroll
  for (int o = 1; o < 64; o <<= 1) num += __shfl_xor(num, o);
  float av = alpha + ((lane < TT) ? endt[lane] : 0.f);
  float m2 = rfl(av);
  float ex = (lane < TT) ? __expf(av - m2) : 0.f;
  #pragma unroll
  for (int o = 1; o < 64; o <<= 1) ex += __shfl_xor(ex, o);
  if (lane == 0) {
    float denom = m2 + __logf(ex);
    float res = (start[yn[0]] + endt[yn[BB - 1]] + num) - denom;
    atomicAdd(out, res);
  }
}

// ---------------------------------------------------------------------------
extern "C" void kernel_launch(void* const* d_in, const int* in_sizes, int n_in,
                              void* d_out, int out_size, void* d_ws, size_t ws_size,
                              hipStream_t stream) {
  const float* x     = (const float*)d_in[0];
  const int*   y     = (const int*)d_in[1];
  const float* Wihf  = (const float*)d_in[2];
  const float* Whhf  = (const float*)d_in[3];
  const float* bihf  = (const float*)d_in[4];
  const float* bhhf  = (const float*)d_in[5];
  const float* Wihb  = (const float*)d_in[6];
  const float* Whhb  = (const float*)d_in[7];
  const float* bihb  = (const float*)d_in[8];
  const float* bhhb  = (const float*)d_in[9];
  const float* Wtag  = (const float*)d_in[10];
  const float* btag  = (const float*)d_in[11];
  const float* stt   = (const float*)d_in[12];
  const float* endt  = (const float*)d_in[13];
  const float* trans = (const float*)d_in[14];

  char* w = (char*)d_ws;
  unsigned short* Wfrag = (unsigned short*)w;  w += 128 * 1024;
  unsigned short* xpT0  = (unsigned short*)w;  w += (size_t)512 * 16 * 208 * 16;  // 27.3 MB
  unsigned short* xpT1  = (unsigned short*)w;  w += (size_t)512 * 16 * 208 * 16;
  float* plogF = (float*)w;  w += (size_t)131072 * 20 * 4;
  float* plogB = (float*)w;  w += (size_t)131072 * 20 * 4;

  hipMemsetAsync(d_out, 0, sizeof(float) * out_size, stream);

  k_cvtW<<<23, 256, 0, stream>>>(Wihf, Wihb, Wfrag);
  k_inproj<<<1024, 256, 0, stream>>>(x, Wfrag, bihf, bhhf, bihb, bhhb, xpT0, xpT1);
  k_rnn<<<256, 256, 0, stream>>>(xpT0, xpT1, Whhf, Whhb, Wtag, plogF, plogB);
  k_crf<<<128, 256, 0, stream>>>(plogF, plogB, btag, y, stt, endt, trans, (float*)d_out);
}

// Round 6
// 400.743 us; speedup vs baseline: 1.0273x; 1.0273x over previous
//
#include <hip/hip_runtime.h>
#include <math.h>

#define SS 512
#define BB 256
#define DIN 202
#define HH 100
#define TT 19

typedef short short8 __attribute__((ext_vector_type(8)));
typedef float f32x4 __attribute__((ext_vector_type(4)));

#define MFMA16(A, B, C) __builtin_amdgcn_mfma_f32_16x16x32_bf16(A, B, C, 0, 0, 0)

__device__ __forceinline__ float rl(float v, int i) {
    return __int_as_float(__builtin_amdgcn_readlane(__float_as_int(v), i));
}
__device__ __forceinline__ float rfl(float v) {
    return __int_as_float(__builtin_amdgcn_readfirstlane(__float_as_int(v)));
}
__device__ __forceinline__ unsigned short f2bf(float f) {
  unsigned u = __float_as_uint(f);
  u += 0x7fff + ((u >> 16) & 1);   // RNE
  return (unsigned short)(u >> 16);
}
__device__ __forceinline__ float bf2f(unsigned v) {
  return __int_as_float((int)(v << 16));
}
__device__ __forceinline__ float fast_tanh(float z) {
  float e = __expf(2.f * z);
  return (e - 1.f) * __fdividef(1.f, e + 1.f);
}
__device__ __forceinline__ void gl_lds16(const void* g, void* l) {
  __builtin_amdgcn_global_load_lds(
      (const __attribute__((address_space(1))) unsigned int*)g,
      (__attribute__((address_space(3))) unsigned int*)l, 16, 0, 0);
}
// v_cvt_pk_bf16_f32: 2 f32 -> packed 2x bf16 (RNE), 1 inst replaces ~10.
__device__ __forceinline__ unsigned cvt_pk_bf16(float lo, float hi) {
  unsigned r;
  asm("v_cvt_pk_bf16_f32 %0, %1, %2" : "=v"(r) : "v"(lo), "v"(hi));
  return r;
}
__device__ __forceinline__ uint2 pack_tanh_pk(f32x4 a) {
  float h0 = fast_tanh(a[0]), h1 = fast_tanh(a[1]);
  float h2 = fast_tanh(a[2]), h3 = fast_tanh(a[3]);
  uint2 v;
  v.x = cvt_pk_bf16(h0, h1);
  v.y = cvt_pk_bf16(h2, h3);
  return v;
}
__device__ __forceinline__ uint2 pack_raw_pk(f32x4 a) {
  uint2 v;
  v.x = cvt_pk_bf16(a[0], a[1]);
  v.y = cvt_pk_bf16(a[2], a[3]);
  return v;
}

// ---------------------------------------------------------------------------
// K0: pack W = [Wf;Wb] (200x202 fp32) into frag-linear bf16 tiles.
// ---------------------------------------------------------------------------
__global__ __launch_bounds__(256) void k_cvtW(
    const float* __restrict__ Wf, const float* __restrict__ Wb,
    unsigned short* __restrict__ Wfrag) {
  int w = blockIdx.x * 256 + threadIdx.x;
  if (w >= 7 * 13 * 64) return;
  int kc = w / (13 * 64);
  int r = w % (13 * 64);
  int ft = r >> 6, l = r & 63;
  int nn = ft * 16 + (l & 15);
  int kb = kc * 32 + (l >> 4) * 8;
  union { unsigned short s[8]; int4 v; } pk;
  #pragma unroll
  for (int e = 0; e < 8; ++e) {
    int k = kb + e;
    float vv = 0.f;
    if (k < DIN) {
      if (nn < 100) vv = Wf[(size_t)nn * DIN + k];
      else if (nn < 200) vv = Wb[(size_t)(nn - 100) * DIN + k];
    }
    pk.s[e] = f2bf(vv);
  }
  *(int4*)&Wfrag[(size_t)w * 8] = pk.v;
}

// ---------------------------------------------------------------------------
// K1: input projection (bf16 MFMA), LDS-staged epilogue into the xpT tiled
// layout k_rnn streams: xpT_d[s][bgrp(16)][u8(13)][nn(16)][8 bf16].
// ---------------------------------------------------------------------------
__global__ __launch_bounds__(256) void k_inproj(
    const float* __restrict__ x, const unsigned short* __restrict__ Wfrag,
    const float* __restrict__ bihf, const float* __restrict__ bhhf,
    const float* __restrict__ bihb, const float* __restrict__ bhhb,
    unsigned short* __restrict__ xpT0, unsigned short* __restrict__ xpT1) {
  __shared__ __align__(16) char smem_raw[28672];
  __shared__ float lbias[208];
  short* lA = (short*)smem_raw;
  short* lB = (short*)(smem_raw + 8192);
  const int t = threadIdx.x;
  const int m0 = blockIdx.x * 128;
  const int s_idx = m0 >> 8;
  const int bhalf = (m0 >> 7) & 1;
  const int wv = t >> 6, lane = t & 63;
  const int li = lane & 15;

  if (t < 208) {
    float bv = 0.f;
    if (t < 100) bv = bihf[t] + bhhf[t];
    else if (t < 200) bv = bihb[t - 100] + bhhb[t - 100];
    lbias[t] = bv;
  }

  f32x4 acc[2][13];
  #pragma unroll
  for (int mf = 0; mf < 2; ++mf)
    #pragma unroll
    for (int nf = 0; nf < 13; ++nf)
      acc[mf][nf] = (f32x4){0.f, 0.f, 0.f, 0.f};

  for (int kc = 0; kc < 7; ++kc) {
    const int k0 = kc * 32;
    __syncthreads();
    #pragma unroll
    for (int r = 0; r < 2; ++r) {
      int u = t + 256 * r;
      int ft = u >> 6, ul = u & 63;
      int i = ul & 15, kq = ul >> 4;
      int kbase = k0 + kq * 8;
      const float* src = x + (size_t)(m0 + ft * 16 + i) * DIN + kbase;
      union { unsigned short s[8]; int4 v; } pk;
      if (kbase + 7 < DIN) {
        float2 v0 = *(const float2*)(src);
        float2 v1 = *(const float2*)(src + 2);
        float2 v2 = *(const float2*)(src + 4);
        float2 v3 = *(const float2*)(src + 6);
        pk.s[0] = f2bf(v0.x); pk.s[1] = f2bf(v0.y);
        pk.s[2] = f2bf(v1.x); pk.s[3] = f2bf(v1.y);
        pk.s[4] = f2bf(v2.x); pk.s[5] = f2bf(v2.y);
        pk.s[6] = f2bf(v3.x); pk.s[7] = f2bf(v3.y);
      } else {
        #pragma unroll
        for (int e = 0; e < 8; ++e)
          pk.s[e] = (kbase + e < DIN) ? f2bf(src[e]) : 0;
      }
      *(int4*)&lA[ft * 512 + ul * 8] = pk.v;
    }
    #pragma unroll
    for (int i = 0; i < 4; ++i) {
      int j = i * 4 + wv;
      if (j < 13)
        gl_lds16(Wfrag + ((size_t)(kc * 13 + j)) * 512, &lB[j * 512]);
    }
    __syncthreads();
    short8 a0 = *(const short8*)&lA[(2 * wv + 0) * 512 + lane * 8];
    short8 a1 = *(const short8*)&lA[(2 * wv + 1) * 512 + lane * 8];
    #pragma unroll
    for (int nf = 0; nf < 13; ++nf) {
      short8 b = *(const short8*)&lB[nf * 512 + lane * 8];
      acc[0][nf] = MFMA16(a0, b, acc[0][nf]);
      acc[1][nf] = MFMA16(a1, b, acc[1][nf]);
    }
  }
  __syncthreads();
  unsigned short* ep = (unsigned short*)smem_raw;  // [128][112]
  float biasv[13];
  #pragma unroll
  for (int nf = 0; nf < 13; ++nf) biasv[nf] = lbias[nf * 16 + li];
  const int r0 = (lane >> 4) * 4;
  #pragma unroll
  for (int d = 0; d < 2; ++d) {
    if (d == 1) __syncthreads();
    #pragma unroll
    for (int mf = 0; mf < 2; ++mf) {
      int lrb = (2 * wv + mf) * 16 + r0;
      #pragma unroll
      for (int nf = 0; nf < 13; ++nf) {
        int col = nf * 16 + li;
        int c = col - 100 * d;
        if (c >= 0 && c < 100) {
          #pragma unroll
          for (int r = 0; r < 4; ++r)
            ep[(lrb + r) * 112 + c] = f2bf(acc[mf][nf][r] + biasv[nf]);
        }
      }
    }
    __syncthreads();
    unsigned short* dst0 = d ? xpT1 : xpT0;
    #pragma unroll
    for (int it = 0; it < 7; ++it) {
      int u = t + 256 * it;
      if (u < 1664) {
        int bgrpL = u / 208;
        int rem = u - bgrpL * 208;
        int u8 = rem >> 4, nn = rem & 15;
        int lr = bgrpL * 16 + nn;
        int4 v = *(const int4*)&ep[lr * 112 + u8 * 8];
        size_t off = ((((size_t)s_idx * 16 + bhalf * 8 + bgrpL) * 13 + u8) * 16 + nn) * 8;
        *(int4*)(dst0 + off) = v;
      }
    }
  }
}

// ---------------------------------------------------------------------------
// K2 v12 (R6): PHASE-SPLIT step body. R5 post-mortem: per-SIMD tile
// throughput identical to R3 (~370-380 ns/tile) at VALUBusy 43% — the
// serializer is the per-tile ds_read(seed) AFTER ds_write(ring) program
// order: hipcc won't reorder LDS ops it can't disambiguate, so the 9 tiles
// execute as 9 serialized ~420cy LDS round-trips. Fix: per step, phase A
// issues ALL ds_reads (4 hc + 7 seeds) into regs; phase B all MFMAs
// (reg-only, independent across tiles); phase C all tanh; phase D packs +
// ds_writes. Zero write->read LDS boundaries inside a step. Also: (1) logit
// tiles gated to st >= wu (warmup logits were discarded; flush guard
// hs>=outbase only reads gated-written slots); (2) v_cvt_pk_bf16_f32 pack
// (RNE, bit-same as f2bf; refcheck'd in learn_hip m214v22). Schedule,
// layouts, vmcnt accounting identical to R5 (passed, absmax 0).
// ---------------------------------------------------------------------------
__global__ __launch_bounds__(256, 1) void k_rnn(
    const unsigned short* __restrict__ xpT0, const unsigned short* __restrict__ xpT1,
    const float* __restrict__ Whf, const float* __restrict__ Whb,
    const float* __restrict__ Wtag, float* __restrict__ plogF, float* __restrict__ plogB) {
  const int bid = blockIdx.x;          // 256 blocks: dir(2) x bgrp(16) x p(8)
  const int dir = bid & 1;
  const int bgrp = (bid >> 1) & 15;
  const int b0 = bgrp * 16;
  const int p = bid >> 5;              // 0..7

  const int t = threadIdx.x;
  const int wv = t >> 6, lane = t & 63;
  const int n = lane & 15, q = lane >> 4;

  const int seg = 4 * p + wv;          // 0..31
  const int start = (seg < 2) ? 0 : (16 * seg - 32);   // never negative
  const int outbase = 16 * seg;
  const int wu = outbase - start;            // warmup steps: 0, 16, or 32
  const int nsteps = wu + 16;                // 16, 32, or 48
  const int nch = nsteps >> 2;               // 4, 8, or 12 chunks of 4 steps

  const unsigned short* xpX = dir ? xpT1 : xpT0;
  const float* Whh = dir ? Whb : Whf;
  float* plog = dir ? plogB : plogF;

  // per-chain LDS: ring 2x3328B | xpl 2x13312B | larc 5120B | dummy 16B
  __shared__ __align__(16) char chainmem[4][38416];
  char* cmem = chainmem[wv];
  short* ring = (short*)cmem;                              // 6656 B (2 slots)
  char* xpl = cmem + 6656;                                 // 26624 B
  unsigned short* larc = (unsigned short*)(cmem + 33280);  // 5120 B
  short* dummy = (short*)(cmem + 38400);                   // 16 B

  // zero ring (both slots) + dummy — same-wave, no barrier needed
  for (int i = lane; i < 1664; i += 64) ((int*)ring)[i] = 0;
  if (lane < 8) dummy[lane] = 0;

  // ---- one-time A-fragment load: all 9 tiles in this wave ----
  short8 af[9][4];
  #pragma unroll
  for (int w = 0; w < 9; ++w) {
    const float* base = nullptr;
    if (w < 7) {
      int m = 16 * w + n;
      if (m < HH) base = Whh + (size_t)m * HH;
    } else if (w == 7) {
      if (n < TT) base = Wtag + (size_t)n * (2 * HH) + dir * HH;
    } else {
      int tA = 16 + n;
      if (tA < TT) base = Wtag + (size_t)tA * (2 * HH) + dir * HH;
    }
    #pragma unroll
    for (int q2 = 0; q2 < 4; ++q2) {
      union { unsigned short s[8]; short8 v; } pa;
      #pragma unroll
      for (int e = 0; e < 8; ++e) {
        int k = 32 * q2 + 8 * q + e;
        pa.s[e] = (base && k < HH) ? f2bf(base[k]) : 0;
      }
      af[w][q2] = pa.v;
    }
  }

  // xp unit precompute: 13 x 1KB units per 4-step chunk image [4s][3328B]
  int sl_[13], off_[13];
  #pragma unroll
  for (int u = 0; u < 13; ++u) {
    int b = u * 1024 + lane * 16;
    sl_[u] = b / 3328;
    off_[u] = b - sl_[u] * 3328 + bgrp * 3328;
  }

  auto issue_chunk = [&](int cc, int buf) {
    int s0 = start + cc * 4;
    #pragma unroll
    for (int u = 0; u < 13; ++u) {
      int s = s0 + sl_[u];
      int sq = dir ? (511 - s) : s;
      gl_lds16((const char*)xpX + (size_t)sq * 53248 + off_[u],
               xpl + buf * 13312 + u * 1024);
    }
  };

  const int offWq = ((q >> 1) * 16 + n) * 16 + (q & 1) * 8;  // + w*512
  const f32x4 z4 = {0.f, 0.f, 0.f, 0.f};

  issue_chunk(0, 0);

  for (int cc = 0; cc < nch; ++cc) {
    if (cc + 1 < nch) {
      issue_chunk(cc + 1, (cc + 1) & 1);
      asm volatile("s_waitcnt vmcnt(13)" ::: "memory");
    } else {
      asm volatile("s_waitcnt vmcnt(0)" ::: "memory");
    }
    __builtin_amdgcn_sched_barrier(0);
    const char* xb = xpl + (cc & 1) * 13312;

    #pragma unroll
    for (int sl = 0; sl < 4; ++sl) {
      const int st = cc * 4 + sl;
      const int cur = st & 1, nxt = cur ^ 1;
      short* rc = ring + cur * 1664;
      short* rn = ring + nxt * 1664;
      // ======== phase A: ALL LDS reads (no writes precede in-step) ========
      short8 hc0 = *(const short8*)(rc + lane * 8);
      short8 hc1 = *(const short8*)(rc + 512 + lane * 8);
      short8 hc2 = *(const short8*)(rc + 1024 + lane * 8);
      short8 hc3 = *(const short8*)((q == 0) ? (rc + 1536 + n * 8) : dummy);
      uint2 sd[7];
      #pragma unroll
      for (int w = 0; w < 7; ++w) {
        int o = sl * 3328 + w * 512 + offWq;
        if (o > 13304) o = 13304;   // w6 q>=2 pad rows (outputs discarded)
        sd[w] = *(const uint2*)(xb + o);
      }
      // ======== phase B: ALL MFMAs (register-only, tile-independent) ======
      f32x4 a[7];
      #pragma unroll
      for (int w = 0; w < 7; ++w) {
        f32x4 seed = {bf2f(sd[w].x & 0xffffu), bf2f(sd[w].x >> 16),
                      bf2f(sd[w].y & 0xffffu), bf2f(sd[w].y >> 16)};
        f32x4 a0 = MFMA16(af[w][0], hc0, seed);
        f32x4 a1 = MFMA16(af[w][1], hc1, z4);
        a0 = MFMA16(af[w][2], hc2, a0);
        a1 = MFMA16(af[w][3], hc3, a1);
        a[w] = a0 + a1;
      }
      const bool doLog = (st >= wu);   // logits discarded during warmup
      f32x4 l7, l8;
      if (doLog) {
        f32x4 a0 = MFMA16(af[7][0], hc0, z4);
        f32x4 a1 = MFMA16(af[7][1], hc1, z4);
        a0 = MFMA16(af[7][2], hc2, a0);
        a1 = MFMA16(af[7][3], hc3, a1);
        l7 = a0 + a1;
        f32x4 b0 = MFMA16(af[8][0], hc0, z4);
        f32x4 b1 = MFMA16(af[8][1], hc1, z4);
        b0 = MFMA16(af[8][2], hc2, b0);
        b1 = MFMA16(af[8][3], hc3, b1);
        l8 = b0 + b1;
      }
      // ======== phase C+D: tanh, cvt_pk pack, ALL LDS writes ==============
      #pragma unroll
      for (int w = 0; w < 7; ++w) {
        uint2 val = pack_tanh_pk(a[w]);
        if (w < 6) {
          *(uint2*)((char*)rn + (w >> 1) * 1024 +
                    ((2 * (w & 1) + (q >> 1)) * 16 + n) * 16 + (q & 1) * 8) = val;
        } else if (q == 0) {
          *(uint2*)((char*)rn + 3072 + n * 16) = val;
        }
      }
      if (doLog) {
        const int ar = ((cc & 1) * 4 + sl) * 16;
        uint2 v7 = pack_raw_pk(l7);
        *(uint2*)&larc[(ar + n) * 20 + 4 * q] = v7;
        if (q == 0) {
          uint2 v8 = pack_raw_pk(l8);
          *(uint2*)&larc[(ar + n) * 20 + 16] = v8;
        }
      }
    }
    // ---- flush archive every 2 chunks (8 steps) ----
    if (cc & 1) {
      int st0 = (cc - 1) * 4;
      #pragma unroll
      for (int j = 0; j < 2; ++j) {
        int fp = lane + 64 * j;
        int sl2 = fp >> 4, nn2 = fp & 15;
        int hs = start + st0 + sl2 - 1;
        if (hs >= outbase) {
          int pos = dir ? (511 - hs) : hs;
          float* dst = plog + ((size_t)pos * 256 + b0 + nn2) * 20;
          const unsigned short* src = &larc[(sl2 * 16 + nn2) * 20];
          #pragma unroll
          for (int j5 = 0; j5 < 5; ++j5) {
            uint2 rv = *(const uint2*)&src[j5 * 4];
            float4 o;
            o.x = bf2f(rv.x & 0xffffu); o.y = bf2f(rv.x >> 16);
            o.z = bf2f(rv.y & 0xffffu); o.w = bf2f(rv.y >> 16);
            *(float4*)&dst[j5 * 4] = o;
          }
        }
      }
    }
  }

  // ---- final logits for position start+nsteps-1 (h in ring slot 0) ----
  {
    short* rc = ring;   // nsteps even -> final h in slot 0
    short8 hc0 = *(const short8*)(rc + lane * 8);
    short8 hc1 = *(const short8*)(rc + 512 + lane * 8);
    short8 hc2 = *(const short8*)(rc + 1024 + lane * 8);
    short8 hc3 = *(const short8*)((q == 0) ? (rc + 1536 + n * 8) : dummy);
    int hs = start + nsteps - 1;
    int pos = dir ? (511 - hs) : hs;
    float* dst = plog + ((size_t)pos * 256 + b0 + n) * 20;
    #pragma unroll
    for (int w = 7; w < 9; ++w) {
      f32x4 a0 = MFMA16(af[w][0], hc0, z4);
      f32x4 a1 = MFMA16(af[w][1], hc1, z4);
      a0 = MFMA16(af[w][2], hc2, a0);
      a1 = MFMA16(af[w][3], hc3, a1);
      f32x4 a = a0 + a1;
      if (w == 7) {
        #pragma unroll
        for (int r = 0; r < 4; ++r) dst[4 * q + r] = a[r];
      } else if (q == 0) {
        #pragma unroll
        for (int r = 0; r < 4; ++r) dst[16 + r] = a[r];
      }
    }
  }
}

// ---------------------------------------------------------------------------
// K4 (FUSED softmax+CRF): one wave per sequence (n = s index, L = BB).
// ---------------------------------------------------------------------------
__global__ __launch_bounds__(256) void k_crf(
    const float* __restrict__ plogF, const float* __restrict__ plogB,
    const float* __restrict__ btag, const int* __restrict__ y,
    const float* __restrict__ start, const float* __restrict__ endt,
    const float* __restrict__ trans, float* __restrict__ out) {
  __shared__ float ltr[TT * TT];
  __shared__ float ltb[20];
  __shared__ float lem[4][64 * 21];
  const int t = threadIdx.x;
  const int wave = t >> 6, lane = t & 63;
  const int n = blockIdx.x * 4 + wave;
  for (int i = t; i < TT * TT; i += 256) ltr[i] = trans[i];
  if (t < 20) ltb[t] = (t < TT) ? btag[t] : 0.f;
  __syncthreads();
  const int* yn = y + n * BB;
  float Ereg[TT];
  #pragma unroll
  for (int i = 0; i < TT; ++i) Ereg[i] = (lane < TT) ? __expf(ltr[i * TT + lane]) : 0.f;
  float num = 0.f;
  float alpha = -1e30f;
  for (int c = 0; c < 4; ++c) {
    const size_t gbase = ((size_t)n * BB + c * 64) * 20;
    for (int u = lane; u < 1280; u += 64) {
      int row = u / 20, col = u - row * 20;
      lem[wave][row * 21 + col] = plogF[gbase + u] + plogB[gbase + u] + ltb[col];
    }
    {
      float vv[TT];
      float mx = -1e30f;
      #pragma unroll
      for (int j = 0; j < TT; ++j) { vv[j] = lem[wave][lane * 21 + j]; mx = fmaxf(mx, vv[j]); }
      float ssum = 0.f;
      #pragma unroll
      for (int j = 0; j < TT; ++j) { vv[j] = __expf(vv[j] - mx); ssum += vv[j]; }
      float inv = __fdividef(1.f, ssum);
      #pragma unroll
      for (int j = 0; j < TT; ++j) lem[wave][lane * 21 + j] = vv[j] * inv;
    }
    {
      int l = c * 64 + lane;
      int yt = yn[l];
      num += lem[wave][lane * 21 + yt];
      if (l < BB - 1) num += ltr[yt * TT + yn[l + 1]];
    }
    int llstart = 0;
    if (c == 0) {
      alpha = (lane < TT) ? (start[lane] + lem[wave][lane]) : -1e30f;
      llstart = 1;
    }
    for (int ll = llstart; ll < 64; ++ll) {
      float m = rfl(alpha);
      float ea = __expf(alpha - m);
      float s0 = 0.f, s1 = 0.f;
      #pragma unroll
      for (int i = 0; i < TT; i += 2) {
        s0 = fmaf(rl(ea, i), Ereg[i], s0);
        if (i + 1 < TT) s1 = fmaf(rl(ea, i + 1), Ereg[i + 1], s1);
      }
      float ssum = s0 + s1;
      float em_l = (lane < TT) ? lem[wave][ll * 21 + lane] : 0.f;
      alpha = em_l + m + __logf(ssum);
    }
  }
  #pragma unroll
  for (int o = 1; o < 64; o <<= 1) num += __shfl_xor(num, o);
  float av = alpha + ((lane < TT) ? endt[lane] : 0.f);
  float m2 = rfl(av);
  float ex = (lane < TT) ? __expf(av - m2) : 0.f;
  #pragma unroll
  for (int o = 1; o < 64; o <<= 1) ex += __shfl_xor(ex, o);
  if (lane == 0) {
    float denom = m2 + __logf(ex);
    float res = (start[yn[0]] + endt[yn[BB - 1]] + num) - denom;
    atomicAdd(out, res);
  }
}

// ---------------------------------------------------------------------------
extern "C" void kernel_launch(void* const* d_in, const int* in_sizes, int n_in,
                              void* d_out, int out_size, void* d_ws, size_t ws_size,
                              hipStream_t stream) {
  const float* x     = (const float*)d_in[0];
  const int*   y     = (const int*)d_in[1];
  const float* Wihf  = (const float*)d_in[2];
  const float* Whhf  = (const float*)d_in[3];
  const float* bihf  = (const float*)d_in[4];
  const float* bhhf  = (const float*)d_in[5];
  const float* Wihb  = (const float*)d_in[6];
  const float* Whhb  = (const float*)d_in[7];
  const float* bihb  = (const float*)d_in[8];
  const float* bhhb  = (const float*)d_in[9];
  const float* Wtag  = (const float*)d_in[10];
  const float* btag  = (const float*)d_in[11];
  const float* stt   = (const float*)d_in[12];
  const float* endt  = (const float*)d_in[13];
  const float* trans = (const float*)d_in[14];

  char* w = (char*)d_ws;
  unsigned short* Wfrag = (unsigned short*)w;  w += 128 * 1024;
  unsigned short* xpT0  = (unsigned short*)w;  w += (size_t)512 * 16 * 208 * 16;  // 27.3 MB
  unsigned short* xpT1  = (unsigned short*)w;  w += (size_t)512 * 16 * 208 * 16;
  float* plogF = (float*)w;  w += (size_t)131072 * 20 * 4;
  float* plogB = (float*)w;  w += (size_t)131072 * 20 * 4;

  hipMemsetAsync(d_out, 0, sizeof(float) * out_size, stream);

  k_cvtW<<<23, 256, 0, stream>>>(Wihf, Wihb, Wfrag);
  k_inproj<<<1024, 256, 0, stream>>>(x, Wfrag, bihf, bhhf, bihb, bhhb, xpT0, xpT1);
  k_rnn<<<256, 256, 0, stream>>>(xpT0, xpT1, Whhf, Whhb, Wtag, plogF, plogB);
  k_crf<<<128, 256, 0, stream>>>(plogF, plogB, btag, y, stt, endt, trans, (float*)d_out);
}

// Round 7
// 357.478 us; speedup vs baseline: 1.1516x; 1.1210x over previous
//
#include <hip/hip_runtime.h>
#include <math.h>

#define SS 512
#define BB 256
#define DIN 202
#define HH 100
#define TT 19

typedef short short8 __attribute__((ext_vector_type(8)));
typedef float f32x4 __attribute__((ext_vector_type(4)));

#define MFMA16(A, B, C) __builtin_amdgcn_mfma_f32_16x16x32_bf16(A, B, C, 0, 0, 0)

__device__ __forceinline__ float rl(float v, int i) {
    return __int_as_float(__builtin_amdgcn_readlane(__float_as_int(v), i));
}
__device__ __forceinline__ float rfl(float v) {
    return __int_as_float(__builtin_amdgcn_readfirstlane(__float_as_int(v)));
}
__device__ __forceinline__ unsigned short f2bf(float f) {
  unsigned u = __float_as_uint(f);
  u += 0x7fff + ((u >> 16) & 1);   // RNE
  return (unsigned short)(u >> 16);
}
__device__ __forceinline__ float bf2f(unsigned v) {
  return __int_as_float((int)(v << 16));
}
__device__ __forceinline__ float fast_tanh(float z) {
  float e = __expf(2.f * z);
  return (e - 1.f) * __fdividef(1.f, e + 1.f);
}
__device__ __forceinline__ void gl_lds16(const void* g, void* l) {
  __builtin_amdgcn_global_load_lds(
      (const __attribute__((address_space(1))) unsigned int*)g,
      (__attribute__((address_space(3))) unsigned int*)l, 16, 0, 0);
}
// v_cvt_pk_bf16_f32: RNE, bit-identical to f2bf (verified R6, absmax 0).
__device__ __forceinline__ unsigned cvt_pk_bf16(float lo, float hi) {
  unsigned r;
  asm("v_cvt_pk_bf16_f32 %0, %1, %2" : "=v"(r) : "v"(lo), "v"(hi));
  return r;
}
__device__ __forceinline__ uint2 pack_tanh_pk(f32x4 a) {
  float h0 = fast_tanh(a[0]), h1 = fast_tanh(a[1]);
  float h2 = fast_tanh(a[2]), h3 = fast_tanh(a[3]);
  uint2 v;
  v.x = cvt_pk_bf16(h0, h1);
  v.y = cvt_pk_bf16(h2, h3);
  return v;
}
__device__ __forceinline__ uint2 pack_raw_pk(f32x4 a) {
  uint2 v;
  v.x = cvt_pk_bf16(a[0], a[1]);
  v.y = cvt_pk_bf16(a[2], a[3]);
  return v;
}
__device__ __forceinline__ f32x4 seed_from(const void* base, int off) {
  uint2 s = *(const uint2*)((const char*)base + off);
  return (f32x4){bf2f(s.x & 0xffffu), bf2f(s.x >> 16),
                 bf2f(s.y & 0xffffu), bf2f(s.y >> 16)};
}

// ---------------------------------------------------------------------------
// K0: pack W = [Wf;Wb] (200x202 fp32) into frag-linear bf16 tiles.
// ---------------------------------------------------------------------------
__global__ __launch_bounds__(256) void k_cvtW(
    const float* __restrict__ Wf, const float* __restrict__ Wb,
    unsigned short* __restrict__ Wfrag) {
  int w = blockIdx.x * 256 + threadIdx.x;
  if (w >= 7 * 13 * 64) return;
  int kc = w / (13 * 64);
  int r = w % (13 * 64);
  int ft = r >> 6, l = r & 63;
  int nn = ft * 16 + (l & 15);
  int kb = kc * 32 + (l >> 4) * 8;
  union { unsigned short s[8]; int4 v; } pk;
  #pragma unroll
  for (int e = 0; e < 8; ++e) {
    int k = kb + e;
    float vv = 0.f;
    if (k < DIN) {
      if (nn < 100) vv = Wf[(size_t)nn * DIN + k];
      else if (nn < 200) vv = Wb[(size_t)(nn - 100) * DIN + k];
    }
    pk.s[e] = f2bf(vv);
  }
  *(int4*)&Wfrag[(size_t)w * 8] = pk.v;
}

// ---------------------------------------------------------------------------
// K1: input projection (bf16 MFMA), LDS-staged epilogue into the xpT tiled
// layout k_rnn streams: xpT_d[s][bgrp(16)][u8(13)][nn(16)][8 bf16].
// ---------------------------------------------------------------------------
__global__ __launch_bounds__(256) void k_inproj(
    const float* __restrict__ x, const unsigned short* __restrict__ Wfrag,
    const float* __restrict__ bihf, const float* __restrict__ bhhf,
    const float* __restrict__ bihb, const float* __restrict__ bhhb,
    unsigned short* __restrict__ xpT0, unsigned short* __restrict__ xpT1) {
  __shared__ __align__(16) char smem_raw[28672];
  __shared__ float lbias[208];
  short* lA = (short*)smem_raw;
  short* lB = (short*)(smem_raw + 8192);
  const int t = threadIdx.x;
  const int m0 = blockIdx.x * 128;
  const int s_idx = m0 >> 8;
  const int bhalf = (m0 >> 7) & 1;
  const int wv = t >> 6, lane = t & 63;
  const int li = lane & 15;

  if (t < 208) {
    float bv = 0.f;
    if (t < 100) bv = bihf[t] + bhhf[t];
    else if (t < 200) bv = bihb[t - 100] + bhhb[t - 100];
    lbias[t] = bv;
  }

  f32x4 acc[2][13];
  #pragma unroll
  for (int mf = 0; mf < 2; ++mf)
    #pragma unroll
    for (int nf = 0; nf < 13; ++nf)
      acc[mf][nf] = (f32x4){0.f, 0.f, 0.f, 0.f};

  for (int kc = 0; kc < 7; ++kc) {
    const int k0 = kc * 32;
    __syncthreads();
    #pragma unroll
    for (int r = 0; r < 2; ++r) {
      int u = t + 256 * r;
      int ft = u >> 6, ul = u & 63;
      int i = ul & 15, kq = ul >> 4;
      int kbase = k0 + kq * 8;
      const float* src = x + (size_t)(m0 + ft * 16 + i) * DIN + kbase;
      union { unsigned short s[8]; int4 v; } pk;
      if (kbase + 7 < DIN) {
        float2 v0 = *(const float2*)(src);
        float2 v1 = *(const float2*)(src + 2);
        float2 v2 = *(const float2*)(src + 4);
        float2 v3 = *(const float2*)(src + 6);
        pk.s[0] = f2bf(v0.x); pk.s[1] = f2bf(v0.y);
        pk.s[2] = f2bf(v1.x); pk.s[3] = f2bf(v1.y);
        pk.s[4] = f2bf(v2.x); pk.s[5] = f2bf(v2.y);
        pk.s[6] = f2bf(v3.x); pk.s[7] = f2bf(v3.y);
      } else {
        #pragma unroll
        for (int e = 0; e < 8; ++e)
          pk.s[e] = (kbase + e < DIN) ? f2bf(src[e]) : 0;
      }
      *(int4*)&lA[ft * 512 + ul * 8] = pk.v;
    }
    #pragma unroll
    for (int i = 0; i < 4; ++i) {
      int j = i * 4 + wv;
      if (j < 13)
        gl_lds16(Wfrag + ((size_t)(kc * 13 + j)) * 512, &lB[j * 512]);
    }
    __syncthreads();
    short8 a0 = *(const short8*)&lA[(2 * wv + 0) * 512 + lane * 8];
    short8 a1 = *(const short8*)&lA[(2 * wv + 1) * 512 + lane * 8];
    #pragma unroll
    for (int nf = 0; nf < 13; ++nf) {
      short8 b = *(const short8*)&lB[nf * 512 + lane * 8];
      acc[0][nf] = MFMA16(a0, b, acc[0][nf]);
      acc[1][nf] = MFMA16(a1, b, acc[1][nf]);
    }
  }
  __syncthreads();
  unsigned short* ep = (unsigned short*)smem_raw;  // [128][112]
  float biasv[13];
  #pragma unroll
  for (int nf = 0; nf < 13; ++nf) biasv[nf] = lbias[nf * 16 + li];
  const int r0 = (lane >> 4) * 4;
  #pragma unroll
  for (int d = 0; d < 2; ++d) {
    if (d == 1) __syncthreads();
    #pragma unroll
    for (int mf = 0; mf < 2; ++mf) {
      int lrb = (2 * wv + mf) * 16 + r0;
      #pragma unroll
      for (int nf = 0; nf < 13; ++nf) {
        int col = nf * 16 + li;
        int c = col - 100 * d;
        if (c >= 0 && c < 100) {
          #pragma unroll
          for (int r = 0; r < 4; ++r)
            ep[(lrb + r) * 112 + c] = f2bf(acc[mf][nf][r] + biasv[nf]);
        }
      }
    }
    __syncthreads();
    unsigned short* dst0 = d ? xpT1 : xpT0;
    #pragma unroll
    for (int it = 0; it < 7; ++it) {
      int u = t + 256 * it;
      if (u < 1664) {
        int bgrpL = u / 208;
        int rem = u - bgrpL * 208;
        int u8 = rem >> 4, nn = rem & 15;
        int lr = bgrpL * 16 + nn;
        int4 v = *(const int4*)&ep[lr * 112 + u8 * 8];
        size_t off = ((((size_t)s_idx * 16 + bhalf * 8 + bgrpL) * 13 + u8) * 16 + nn) * 8;
        *(int4*)(dst0 + off) = v;
      }
    }
  }
}

// ---------------------------------------------------------------------------
// K2 v13 (R7): DUAL-CHAIN x 9-WAVE balanced scan. R5/R6 post-mortem: the
// wave-private design spills weight regs (needs ~230 VGPR, af alone 144) ->
// scratch round-trips every step; abandoned. Best structure is R3 (9 waves,
// 1 tile/wave, 16 weight VGPRs, barrier/step, 79.6us). R3 also showed the
// ~2000cy barrier-step floor is FLAT in per-wave work (R0->R3 halved work,
// step 883->829ns). Exploit: amortize the floor over TWO chains (R2's
// proven 16-segment pairing: chains p and p+8, 32 outputs + 32 warmup = 64
// steps). Each wave does its tile for both chains per step (8 MFMA + 8 tanh
// ~ 550cy issue, still under floor), one barrier serves both. Steps/block
// 96 -> 64. LDS 123.4KB, 1 block/CU. cvt_pk packs (bit-identical, R6).
// All per-tile layouts/math cloned from R3 (absmax 0) + R2 (absmax 0).
// ---------------------------------------------------------------------------
__global__ __launch_bounds__(576) void k_rnn(
    const unsigned short* __restrict__ xpT0, const unsigned short* __restrict__ xpT1,
    const float* __restrict__ Whf, const float* __restrict__ Whb,
    const float* __restrict__ Wtag, float* __restrict__ plogF, float* __restrict__ plogB) {
  const int bid = blockIdx.x;            // 256 blocks
  const int dir = bid & 1;
  const int bgrp = (bid >> 1) & 15;
  const int b0 = bgrp * 16;
  const int p = bid >> 5;                // 0..7
  int startc[2], outbasec[2];
  startc[0] = (p == 0) ? 0 : (32 * p - 32);
  outbasec[0] = 32 * p;
  startc[1] = 32 * (p + 8) - 32;
  outbasec[1] = 32 * (p + 8);
  // nch = 8 for all; p=0 ch0 duplicates seg1's outputs bit-identically (R2).

  const float* Whh = dir ? Whb : Whf;
  const unsigned short* xpX = dir ? xpT1 : xpT0;
  float* plog = dir ? plogB : plogF;

  __shared__ short ringc[2][9][3][512];        // 55296 B
  __shared__ short ring3[2][9][128];           //  4608 B
  __shared__ unsigned short xpl[2][13312];     // 53248 B
  __shared__ unsigned short larc[2][2560];     // 10240 B
  __shared__ short dummy16[8];

  const int t = threadIdx.x;
  const int wv = t >> 6, lane = t & 63;
  const int n = lane & 15, q = lane >> 4;

  for (int i = t; i < 3 * 512; i += 576) {
    ringc[0][0][i >> 9][i & 511] = 0;
    ringc[1][0][i >> 9][i & 511] = 0;
  }
  for (int i = t; i < 9 * 128; i += 576) {
    ring3[0][i >> 7][i & 127] = 0;
    ring3[1][i >> 7][i & 127] = 0;
  }
  if (t < 8) dummy16[t] = 0;

  // ---- one-time A-fragment load: wave wv owns one 16-col tile (R3) ----
  short8 af[4];
  #pragma unroll
  for (int q2 = 0; q2 < 4; ++q2) af[q2] = (short8){0,0,0,0,0,0,0,0};
  {
    const float* base = nullptr;
    if (wv < 7) {
      int m = 16 * wv + n;
      if (m < HH) base = Whh + (size_t)m * HH;
    } else if (wv == 7) {
      if (n < TT) base = Wtag + (size_t)n * (2 * HH) + dir * HH;
    } else {
      int tA = 16 + n;
      if (tA < TT) base = Wtag + (size_t)tA * (2 * HH) + dir * HH;
    }
    #pragma unroll
    for (int q2 = 0; q2 < 4; ++q2) {
      union { unsigned short s[8]; short8 v; } pa;
      #pragma unroll
      for (int e = 0; e < 8; ++e) {
        int k = 32 * q2 + 8 * q + e;
        pa.s[e] = (base && k < HH) ? f2bf(base[k]) : 0;
      }
      af[q2] = pa.v;
    }
  }

  // mega-load index precompute: 52 units (26/chain), stride-9 over waves
  int slj[6], remj[6];
  #pragma unroll
  for (int i = 0; i < 6; ++i) {
    int j = i * 9 + wv;
    int jj = (j < 52) ? ((j >= 26) ? (j - 26) : j) : 0;
    int unit = jj * 64 + lane;
    slj[i] = unit / 208;
    remj[i] = unit - slj[i] * 208;
  }

  // seed byte-offset within xpl[ch] for this wave's 16 cols (wv<7)
  const int offW = ((2 * wv + (q >> 1)) * 16 + n) * 16 + (q & 1) * 8;

  for (int cc = 0; cc < 8; ++cc) {
    // ================= mega phase =================
    if (cc > 0) {
      int fch = -1, ft2 = 0;
      if (t < 128) { fch = 0; ft2 = t; }
      else if (t < 256) { fch = 1; ft2 = t - 128; }
      if (fch >= 0) {
        int sl = ft2 >> 4, nn2 = ft2 & 15;
        int hs = startc[fch] + (cc - 1) * 8 - 1 + sl;
        if (hs >= outbasec[fch]) {
          int pos = dir ? (511 - hs) : hs;
          float* dst = plog + ((size_t)pos * 256 + b0 + nn2) * 20;
          const unsigned short* src = &larc[fch][(sl * 16 + nn2) * 20];
          #pragma unroll
          for (int j5 = 0; j5 < 5; ++j5) {
            uint2 rv = *(const uint2*)&src[j5 * 4];
            float4 o;
            o.x = bf2f(rv.x & 0xffffu); o.y = bf2f(rv.x >> 16);
            o.z = bf2f(rv.y & 0xffffu); o.w = bf2f(rv.y >> 16);
            *(float4*)&dst[j5 * 4] = o;
          }
        }
      }
      #pragma unroll
      for (int ch = 0; ch < 2; ++ch) {
        if (t < 192) {
          *(int4*)&ringc[ch][0][t >> 6][(t & 63) * 8] =
              *(const int4*)&ringc[ch][8][t >> 6][(t & 63) * 8];
        } else if (t < 208) {
          int i2 = t - 192;
          *(int4*)&ring3[ch][0][i2 * 8] = *(const int4*)&ring3[ch][8][i2 * 8];
        }
      }
    }
    // bulk xp load for both chains (contiguous 3328-B runs per (s,bgrp))
    #pragma unroll
    for (int i = 0; i < 6; ++i) {
      int j = i * 9 + wv;
      if (j < 52) {
        int ch = (j >= 26) ? 1 : 0;
        int jj = j - 26 * ch;
        int s = startc[ch] + cc * 8 + slj[i];
        int sq = dir ? (511 - s) : s;
        gl_lds16(xpX + (((size_t)sq * 16 + bgrp) * 208 + remj[i]) * 8, &xpl[ch][jj * 512]);
      }
    }
    __syncthreads();   // the only vmcnt-draining barrier per 8 dual-steps

    // ================= 8 inner dual-steps (LDS only) =================
    #pragma unroll
    for (int sl = 0; sl < 8; ++sl) {
      short8 hc[2][4];
      #pragma unroll
      for (int ch = 0; ch < 2; ++ch) {
        hc[ch][0] = *(const short8*)&ringc[ch][sl][0][lane * 8];
        hc[ch][1] = *(const short8*)&ringc[ch][sl][1][lane * 8];
        hc[ch][2] = *(const short8*)&ringc[ch][sl][2][lane * 8];
        hc[ch][3] = *(const short8*)((q == 0) ? &ring3[ch][sl][n * 8] : &dummy16[0]);
      }
      f32x4 z4 = {0.f, 0.f, 0.f, 0.f};
      if (wv < 7) {
        int oW = sl * 3328 + offW;
        if (oW > 26616) oW = 26616;   // wv6 q>=2 pad rows (discarded)
        f32x4 a[2];
        #pragma unroll
        for (int ch = 0; ch < 2; ++ch) {
          f32x4 seed = seed_from(&xpl[ch][0], oW);
          f32x4 a0 = MFMA16(af[0], hc[ch][0], seed);
          f32x4 a1 = MFMA16(af[1], hc[ch][1], z4);
          a0 = MFMA16(af[2], hc[ch][2], a0);
          a1 = MFMA16(af[3], hc[ch][3], a1);
          a[ch] = a0 + a1;
        }
        #pragma unroll
        for (int ch = 0; ch < 2; ++ch) {
          uint2 val = pack_tanh_pk(a[ch]);
          if (wv < 6) {
            *(uint2*)&ringc[ch][sl + 1][wv >> 1]
                [((2 * (wv & 1) + (q >> 1)) * 16 + n) * 8 + 4 * (q & 1)] = val;
          } else if (q == 0) {
            *(uint2*)&ring3[ch][sl + 1][n * 8] = val;
          }
        }
      } else {
        f32x4 a[2];
        #pragma unroll
        for (int ch = 0; ch < 2; ++ch) {
          f32x4 a0 = MFMA16(af[0], hc[ch][0], z4);
          f32x4 a1 = MFMA16(af[1], hc[ch][1], z4);
          a0 = MFMA16(af[2], hc[ch][2], a0);
          a1 = MFMA16(af[3], hc[ch][3], a1);
          a[ch] = a0 + a1;
        }
        #pragma unroll
        for (int ch = 0; ch < 2; ++ch) {
          uint2 v = pack_raw_pk(a[ch]);
          if (wv == 7) {
            *(uint2*)&larc[ch][(sl * 16 + n) * 20 + 4 * q] = v;
          } else if (q == 0) {
            *(uint2*)&larc[ch][(sl * 16 + n) * 20 + 16] = v;
          }
        }
      }
      __syncthreads();
    }
  }
  // final flush of last chunk's archives (both chains)
  {
    int fch = -1, ft2 = 0;
    if (t < 128) { fch = 0; ft2 = t; }
    else if (t < 256) { fch = 1; ft2 = t - 128; }
    if (fch >= 0) {
      int sl = ft2 >> 4, nn2 = ft2 & 15;
      int hs = startc[fch] + 7 * 8 - 1 + sl;
      if (hs >= outbasec[fch]) {
        int pos = dir ? (511 - hs) : hs;
        float* dst = plog + ((size_t)pos * 256 + b0 + nn2) * 20;
        const unsigned short* src = &larc[fch][(sl * 16 + nn2) * 20];
        #pragma unroll
        for (int j5 = 0; j5 < 5; ++j5) {
          uint2 rv = *(const uint2*)&src[j5 * 4];
          float4 o;
          o.x = bf2f(rv.x & 0xffffu); o.y = bf2f(rv.x >> 16);
          o.z = bf2f(rv.y & 0xffffu); o.w = bf2f(rv.y >> 16);
          *(float4*)&dst[j5 * 4] = o;
        }
      }
    }
  }
  // logits for each chain's final h (ring slot 8): waves 7 & 8
  if (wv >= 7) {
    #pragma unroll
    for (int ch = 0; ch < 2; ++ch) {
      short8 hc0 = *(const short8*)&ringc[ch][8][0][lane * 8];
      short8 hc1 = *(const short8*)&ringc[ch][8][1][lane * 8];
      short8 hc2 = *(const short8*)&ringc[ch][8][2][lane * 8];
      short8 hc3 = *(const short8*)((q == 0) ? &ring3[ch][8][n * 8] : &dummy16[0]);
      f32x4 z4 = {0.f, 0.f, 0.f, 0.f};
      f32x4 a0 = MFMA16(af[0], hc0, z4);
      f32x4 a1 = MFMA16(af[1], hc1, z4);
      a0 = MFMA16(af[2], hc2, a0);
      a1 = MFMA16(af[3], hc3, a1);
      f32x4 a = a0 + a1;
      int hs = startc[ch] + 63;
      int pos = dir ? (511 - hs) : hs;
      float* dst = plog + ((size_t)pos * 256 + b0 + n) * 20;
      if (wv == 7) {
        #pragma unroll
        for (int r = 0; r < 4; ++r) dst[4 * q + r] = a[r];
      } else if (q == 0) {
        #pragma unroll
        for (int r = 0; r < 4; ++r) dst[16 + r] = a[r];
      }
    }
  }
}

// ---------------------------------------------------------------------------
// K4 (FUSED softmax+CRF): one wave per sequence (n = s index, L = BB).
// ---------------------------------------------------------------------------
__global__ __launch_bounds__(256) void k_crf(
    const float* __restrict__ plogF, const float* __restrict__ plogB,
    const float* __restrict__ btag, const int* __restrict__ y,
    const float* __restrict__ start, const float* __restrict__ endt,
    const float* __restrict__ trans, float* __restrict__ out) {
  __shared__ float ltr[TT * TT];
  __shared__ float ltb[20];
  __shared__ float lem[4][64 * 21];
  const int t = threadIdx.x;
  const int wave = t >> 6, lane = t & 63;
  const int n = blockIdx.x * 4 + wave;
  for (int i = t; i < TT * TT; i += 256) ltr[i] = trans[i];
  if (t < 20) ltb[t] = (t < TT) ? btag[t] : 0.f;
  __syncthreads();
  const int* yn = y + n * BB;
  float Ereg[TT];
  #pragma unroll
  for (int i = 0; i < TT; ++i) Ereg[i] = (lane < TT) ? __expf(ltr[i * TT + lane]) : 0.f;
  float num = 0.f;
  float alpha = -1e30f;
  for (int c = 0; c < 4; ++c) {
    const size_t gbase = ((size_t)n * BB + c * 64) * 20;
    for (int u = lane; u < 1280; u += 64) {
      int row = u / 20, col = u - row * 20;
      lem[wave][row * 21 + col] = plogF[gbase + u] + plogB[gbase + u] + ltb[col];
    }
    {
      float vv[TT];
      float mx = -1e30f;
      #pragma unroll
      for (int j = 0; j < TT; ++j) { vv[j] = lem[wave][lane * 21 + j]; mx = fmaxf(mx, vv[j]); }
      float ssum = 0.f;
      #pragma unroll
      for (int j = 0; j < TT; ++j) { vv[j] = __expf(vv[j] - mx); ssum += vv[j]; }
      float inv = __fdividef(1.f, ssum);
      #pragma unroll
      for (int j = 0; j < TT; ++j) lem[wave][lane * 21 + j] = vv[j] * inv;
    }
    {
      int l = c * 64 + lane;
      int yt = yn[l];
      num += lem[wave][lane * 21 + yt];
      if (l < BB - 1) num += ltr[yt * TT + yn[l + 1]];
    }
    int llstart = 0;
    if (c == 0) {
      alpha = (lane < TT) ? (start[lane] + lem[wave][lane]) : -1e30f;
      llstart = 1;
    }
    for (int ll = llstart; ll < 64; ++ll) {
      float m = rfl(alpha);
      float ea = __expf(alpha - m);
      float s0 = 0.f, s1 = 0.f;
      #pragma unroll
      for (int i = 0; i < TT; i += 2) {
        s0 = fmaf(rl(ea, i), Ereg[i], s0);
        if (i + 1 < TT) s1 = fmaf(rl(ea, i + 1), Ereg[i + 1], s1);
      }
      float ssum = s0 + s1;
      float em_l = (lane < TT) ? lem[wave][ll * 21 + lane] : 0.f;
      alpha = em_l + m + __logf(ssum);
    }
  }
  #pragma unroll
  for (int o = 1; o < 64; o <<= 1) num += __shfl_xor(num, o);
  float av = alpha + ((lane < TT) ? endt[lane] : 0.f);
  float m2 = rfl(av);
  float ex = (lane < TT) ? __expf(av - m2) : 0.f;
  #pragma unroll
  for (int o = 1; o < 64; o <<= 1) ex += __shfl_xor(ex, o);
  if (lane == 0) {
    float denom = m2 + __logf(ex);
    float res = (start[yn[0]] + endt[yn[BB - 1]] + num) - denom;
    atomicAdd(out, res);
  }
}

// ---------------------------------------------------------------------------
extern "C" void kernel_launch(void* const* d_in, const int* in_sizes, int n_in,
                              void* d_out, int out_size, void* d_ws, size_t ws_size,
                              hipStream_t stream) {
  const float* x     = (const float*)d_in[0];
  const int*   y     = (const int*)d_in[1];
  const float* Wihf  = (const float*)d_in[2];
  const float* Whhf  = (const float*)d_in[3];
  const float* bihf  = (const float*)d_in[4];
  const float* bhhf  = (const float*)d_in[5];
  const float* Wihb  = (const float*)d_in[6];
  const float* Whhb  = (const float*)d_in[7];
  const float* bihb  = (const float*)d_in[8];
  const float* bhhb  = (const float*)d_in[9];
  const float* Wtag  = (const float*)d_in[10];
  const float* btag  = (const float*)d_in[11];
  const float* stt   = (const float*)d_in[12];
  const float* endt  = (const float*)d_in[13];
  const float* trans = (const float*)d_in[14];

  char* w = (char*)d_ws;
  unsigned short* Wfrag = (unsigned short*)w;  w += 128 * 1024;
  unsigned short* xpT0  = (unsigned short*)w;  w += (size_t)512 * 16 * 208 * 16;  // 27.3 MB
  unsigned short* xpT1  = (unsigned short*)w;  w += (size_t)512 * 16 * 208 * 16;
  float* plogF = (float*)w;  w += (size_t)131072 * 20 * 4;
  float* plogB = (float*)w;  w += (size_t)131072 * 20 * 4;

  hipMemsetAsync(d_out, 0, sizeof(float) * out_size, stream);

  k_cvtW<<<23, 256, 0, stream>>>(Wihf, Wihb, Wfrag);
  k_inproj<<<1024, 256, 0, stream>>>(x, Wfrag, bihf, bhhf, bihb, bhhb, xpT0, xpT1);
  k_rnn<<<256, 576, 0, stream>>>(xpT0, xpT1, Whhf, Whhb, Wtag, plogF, plogB);
  k_crf<<<128, 256, 0, stream>>>(plogF, plogB, btag, y, stt, endt, trans, (float*)d_out);
}